// Round 1
// baseline (11614.948 us; speedup 1.0000x reference)
//
#include <hip/hip_runtime.h>
#include <hip/hip_bf16.h>
#include <hip/hip_cooperative_groups.h>

namespace cg = cooperative_groups;

typedef __attribute__((ext_vector_type(8))) short short8;
typedef __attribute__((ext_vector_type(4))) float floatx4;
typedef __hip_bfloat16 bf16;

#define MFMA16(a,b,c) __builtin_amdgcn_mfma_f32_16x16x32_bf16((a),(b),(c),0,0,0)

__device__ __forceinline__ short8 ldf(const bf16* p){ return *(const short8*)p; }
__device__ __forceinline__ float fsig(float x){ return 1.f/(1.f+__expf(-x)); }
__device__ __forceinline__ float ftanh(float x){
  float c = fminf(fmaxf(x,-15.f),15.f);
  float e = __expf(2.f*c);
  return (e-1.f)/(e+1.f);
}

typedef __attribute__((address_space(1))) void gvoid;
typedef __attribute__((address_space(3))) void lvoid;
// async global->LDS, 16B per lane; LDS dest = uniform base + lane*16
__device__ __forceinline__ void stage16(const bf16* g, bf16* l){
  __builtin_amdgcn_global_load_lds((gvoid*)g, (lvoid*)l, 16, 0, 0);
}

// ---------------- weight prep: fp32 [R][C] -> bf16 [C][R] ----------------
__global__ __launch_bounds__(256) void k_transpose(const float* __restrict__ in,
                                                   bf16* __restrict__ out, int R, int C){
  __shared__ float t[32][33];
  int bc = blockIdx.x*32, br = blockIdx.y*32;
  int tx = threadIdx.x & 31, ty = threadIdx.x >> 5;
  #pragma unroll
  for (int i=0;i<32;i+=8) t[ty+i][tx] = in[(size_t)(br+ty+i)*C + bc+tx];
  __syncthreads();
  #pragma unroll
  for (int i=0;i<32;i+=8) out[(size_t)(bc+ty+i)*R + br+tx] = __float2bfloat16(t[tx][ty+i]);
}

__global__ __launch_bounds__(256) void k_cast(const float* __restrict__ in, bf16* __restrict__ out, int n){
  int i = blockIdx.x*256+threadIdx.x;
  if (i<n) out[i] = __float2bfloat16(in[i]);
}

__global__ __launch_bounds__(256) void k_cast_state(const float* __restrict__ st, bf16* __restrict__ pin){
  int i = blockIdx.x*256+threadIdx.x; // 16384
  int r = i >> 6, c = i & 63;
  pin[r*192 + c] = __float2bfloat16(st[i]);
}

__global__ __launch_bounds__(256) void k_acth1(const float* __restrict__ act,
                                               const float* __restrict__ w1,
                                               const float* __restrict__ b1,
                                               bf16* __restrict__ H1){
  int idx = blockIdx.x*256 + threadIdx.x;
  int c = idx & 511; int r = idx >> 9;
  int t = r >> 8, b = r & 255;
  const float* a = act + (b*64 + t)*6;
  float s = b1[c];
  #pragma unroll
  for (int i=0;i<6;i++) s += a[i]*w1[i*512+c];
  H1[r*512+c] = __float2bfloat16(ftanh(s));
}

// ---------------- generic GEMM (setup path only, small shapes) ----------------
__global__ __launch_bounds__(256) void k_gemm16(
  const bf16* __restrict__ A, int sA,
  const bf16* __restrict__ Bt,
  const float* __restrict__ bias,
  bf16* __restrict__ out, int sO, int oO,
  int K, int mode)
{
  int lane = threadIdx.x & 63, wave = threadIdx.x >> 6;
  int lr = lane & 15, lq = lane >> 4;
  int j0 = blockIdx.x*64 + wave*16;
  int m0 = blockIdx.y*16;
  const bf16* Ap = A + (m0+lr)*sA + lq*8;
  const bf16* Bp = Bt + (j0+lr)*K + lq*8;
  floatx4 acc = {0.f,0.f,0.f,0.f};
  #pragma unroll 4
  for (int kb=0; kb<K; kb+=32){
    short8 a = ldf(Ap+kb);
    short8 b = ldf(Bp+kb);
    acc = MFMA16(a, b, acc);
  }
  #pragma unroll
  for (int i=0;i<4;i++){
    int m = m0 + lq*4 + i, j = j0 + lr;
    float v = acc[i] + bias[j];
    if (mode) v = ftanh(v);
    out[m*sO + oO + j] = __float2bfloat16(v);
  }
}

// ---------------- gaussian head (setup: z0) ----------------
__global__ __launch_bounds__(256) void k_gauss(
  const bf16* __restrict__ A, const bf16* __restrict__ Bt,
  const float* __restrict__ bias, const float* __restrict__ eps,
  bf16* __restrict__ out, int K)
{
  int lane = threadIdx.x & 63, wave = threadIdx.x >> 6;
  int lr = lane & 15, lq = lane >> 4;
  int j0 = blockIdx.x*64 + wave*16;
  int m0 = blockIdx.y*16;
  const bf16* Ap = A + (m0+lr)*K + lq*8;
  const bf16* Bm = Bt + (j0+lr)*K + lq*8;
  const bf16* Bl = Bt + (j0+1024+lr)*K + lq*8;
  floatx4 aM = {0.f,0.f,0.f,0.f}, aL = {0.f,0.f,0.f,0.f};
  #pragma unroll 4
  for (int kb=0;kb<K;kb+=32){
    short8 a = ldf(Ap+kb);
    aM = MFMA16(a, ldf(Bm+kb), aM);
    aL = MFMA16(a, ldf(Bl+kb), aL);
  }
  #pragma unroll
  for (int i=0;i<4;i++){
    int m = m0+lq*4+i, j = j0+lr;
    float z = aM[i] + bias[j] + __expf(aL[i] + bias[1024+j]) * eps[m*1024 + j];
    out[m*1024+j] = __float2bfloat16(z);
  }
}

// ---------------- AE gemm: 128x128 LDS tile (was the 123us naive k_gemm16) ----------------
// AEb = H1 @ amlp_w2 + b2 : M=16384, N=512, K=512. grid (4,128).
__global__ __launch_bounds__(256) void k_aev2(
  const bf16* __restrict__ A, const bf16* __restrict__ W,
  const float* __restrict__ bias, bf16* __restrict__ Out)
{
  __shared__ __align__(16) bf16 As[128*32];
  __shared__ __align__(16) bf16 Bs[128*32];
  const int tid = threadIdx.x, lane = tid & 63, w = tid >> 6;
  const int lr = lane & 15, lq = lane >> 4;
  const int mh = (w & 1) * 64, jh = (w >> 1) * 64;
  const int m0 = blockIdx.y * 128, j0 = blockIdx.x * 128;
  const int cA0 = w*128 + lane,      cA1 = w*128 + 64 + lane;
  const int r0 = cA0>>2, o0 = (cA0&3)*8, r1 = cA1>>2, o1 = (cA1&3)*8;
  bf16* lA0 = As + (w*2+0)*512; bf16* lA1 = As + (w*2+1)*512;
  bf16* lB0 = Bs + (w*2+0)*512; bf16* lB1 = Bs + (w*2+1)*512;
  floatx4 acc[4][4] = {};
  for (int kb=0; kb<512; kb+=32){
    stage16(A + (size_t)(m0+r0)*512 + kb + o0, lA0);
    stage16(A + (size_t)(m0+r1)*512 + kb + o1, lA1);
    stage16(W + (size_t)(j0+r0)*512 + kb + o0, lB0);
    stage16(W + (size_t)(j0+r1)*512 + kb + o1, lB1);
    __syncthreads();
    short8 af[4], bfr[4];
    #pragma unroll
    for (int f=0; f<4; f++){
      af[f]  = *(const short8*)&As[(mh + f*16 + lr)*32 + lq*8];
      bfr[f] = *(const short8*)&Bs[(jh + f*16 + lr)*32 + lq*8];
    }
    #pragma unroll
    for (int mf=0; mf<4; mf++)
      #pragma unroll
      for (int jf=0; jf<4; jf++)
        acc[mf][jf] = MFMA16(af[mf], bfr[jf], acc[mf][jf]);
    __syncthreads();
  }
  #pragma unroll
  for (int mf=0; mf<4; mf++)
    #pragma unroll
    for (int jf=0; jf<4; jf++)
      #pragma unroll
      for (int i=0; i<4; i++){
        int m = m0 + mh + mf*16 + lq*4 + i;
        int j = j0 + jh + jf*16 + lr;
        Out[(size_t)m*512 + j] = __float2bfloat16(acc[mf][jf][i] + bias[j]);
      }
}

// ---------------- persistent cooperative scan: all 64 steps in ONE kernel ----------------
// 256 blocks x 256 threads, 1 block/CU, co-resident. Block b: jt = b&63 (XCD b%8 == jt%8
// keeps this XCD's ~2MB weight slice L2-resident for ALL steps), mg = b>>6.
// Each wave owns a 16x16 output tile FULL-K: no LDS reduce, no intra-phase barriers.
// 4 waves of a block share identical B-row addresses -> L1 dedup; weight traffic/step
// drops 252MB -> 63MB vs the old 16-row-m-tile kernels. grid.sync() between phases
// replaces 191 kernel launches.
__global__ __launch_bounds__(256) void k_scan(
  bf16* __restrict__ Zbuf, bf16* __restrict__ Hbuf, const bf16* __restrict__ AEb,
  const bf16* __restrict__ WzT, const bf16* __restrict__ WhT, const bf16* __restrict__ WaT,
  const float* __restrict__ gbih, const float* __restrict__ gbhh,
  const bf16* __restrict__ Lw1T, const float* __restrict__ Lb1,
  const bf16* __restrict__ Lw2T, const float* __restrict__ Lb2,
  const float* __restrict__ epss, bf16* __restrict__ X)
{
  const int lane = threadIdx.x & 63, w = threadIdx.x >> 6;
  const int lr = lane & 15, lq = lane >> 4;
  const int jt = blockIdx.x & 63, mg = blockIdx.x >> 6;
  const int jl = jt*16 + lr;
  const int m0 = mg*64 + w*16;
  const int ar = m0 + lr;

  // t-invariant weight pointers / biases, hoisted out of the scan loop
  const bf16* BzR = WzT + (size_t)jl*1024 + lq*8;
  const bf16* BzU = WzT + (size_t)(jl+1024)*1024 + lq*8;
  const bf16* BzN = WzT + (size_t)(jl+2048)*1024 + lq*8;
  const bf16* BaR = WaT + (size_t)jl*512 + lq*8;
  const bf16* BaU = WaT + (size_t)(jl+1024)*512 + lq*8;
  const bf16* BaN = WaT + (size_t)(jl+2048)*512 + lq*8;
  const bf16* BhR = WhT + (size_t)jl*1024 + lq*8;
  const bf16* BhU = WhT + (size_t)(jl+1024)*1024 + lq*8;
  const bf16* BhN = WhT + (size_t)(jl+2048)*1024 + lq*8;
  const bf16* B1  = Lw1T + (size_t)jl*1024 + lq*8;
  const bf16* B2m = Lw2T + (size_t)jl*1024 + lq*8;
  const bf16* B2l = Lw2T + (size_t)(1024+jl)*1024 + lq*8;
  const float bR = gbih[jl]      + gbhh[jl];
  const float bU = gbih[1024+jl] + gbhh[1024+jl];
  const float bX = gbih[2048+jl], bH = gbhh[2048+jl];
  const float b1 = Lb1[jl];
  const float bmu = Lb2[jl], bls = Lb2[1024+jl];

  cg::grid_group grid = cg::this_grid();

  for (int t=0; t<64; t++){
    const bf16* Zt  = Zbuf + (size_t)t*262144;
    const bf16* Ht  = Hbuf + (size_t)t*262144;
    bf16*       Htn = Hbuf + (size_t)(t+1)*262144;
    bf16*       Ztn = Zbuf + (size_t)(t+1)*262144;
    const bf16* AE  = AEb  + (size_t)t*131072;

    // ---- phase G: GRU cell ----
    floatx4 R={},U={},NX={},NH={};
    {
      const bf16* Ap = Zt + ar*1024 + lq*8;
      #pragma unroll 2
      for (int k=0;k<1024;k+=32){
        short8 a = ldf(Ap+k);
        R  = MFMA16(a, ldf(BzR+k), R);
        U  = MFMA16(a, ldf(BzU+k), U);
        NX = MFMA16(a, ldf(BzN+k), NX);
      }
    }
    {
      const bf16* Ap = AE + ar*512 + lq*8;
      #pragma unroll 2
      for (int k=0;k<512;k+=32){
        short8 a = ldf(Ap+k);
        R  = MFMA16(a, ldf(BaR+k), R);
        U  = MFMA16(a, ldf(BaU+k), U);
        NX = MFMA16(a, ldf(BaN+k), NX);
      }
    }
    {
      const bf16* Ap = Ht + ar*1024 + lq*8;
      #pragma unroll 2
      for (int k=0;k<1024;k+=32){
        short8 a = ldf(Ap+k);
        R  = MFMA16(a, ldf(BhR+k), R);
        U  = MFMA16(a, ldf(BhU+k), U);
        NH = MFMA16(a, ldf(BhN+k), NH);
      }
    }
    #pragma unroll
    for (int i=0;i<4;i++){
      int m = m0 + lq*4 + i;
      float r = fsig(R[i]+bR);
      float u = fsig(U[i]+bU);
      float n = ftanh(NX[i]+bX + r*(NH[i]+bH));
      float h = __bfloat162float(Ht[m*1024+jl]);
      Htn[m*1024+jl] = __float2bfloat16((1.f-u)*n + u*h);
    }
    grid.sync();

    // ---- phase L1: X = tanh(Hn @ Lw1 + b1) ----
    floatx4 C={};
    {
      const bf16* Ap = Htn + ar*1024 + lq*8;
      #pragma unroll 4
      for (int k=0;k<1024;k+=32)
        C = MFMA16(ldf(Ap+k), ldf(B1+k), C);
    }
    #pragma unroll
    for (int i=0;i<4;i++){
      int m = m0 + lq*4 + i;
      X[m*1024+jl] = __float2bfloat16(ftanh(C[i]+b1));
    }
    grid.sync();

    // ---- phase L2: Zn = mu + exp(ls)*eps ----
    floatx4 Mu={},Ls={};
    {
      const bf16* Ap = X + ar*1024 + lq*8;
      #pragma unroll 2
      for (int k=0;k<1024;k+=32){
        short8 a = ldf(Ap+k);
        Mu = MFMA16(a, ldf(B2m+k), Mu);
        Ls = MFMA16(a, ldf(B2l+k), Ls);
      }
    }
    #pragma unroll
    for (int i=0;i<4;i++){
      int m = m0 + lq*4 + i;
      float z = Mu[i]+bmu + __expf(Ls[i]+bls) * epss[(size_t)t*262144 + m*1024 + jl];
      Ztn[m*1024+jl] = __float2bfloat16(z);
    }
    grid.sync();
  }
}

// ---------------- decode: 128x128 LDS-tiled GEMM with global_load_lds ----------------
// Y = tanh([Zb|Hb] @ W^T + bias): M=16384, N=1024, K=2048(2 segs). grid (8,128).
__global__ __launch_bounds__(256) void k_dec1v2(
  const bf16* __restrict__ Zb, const bf16* __restrict__ Hb,
  const bf16* __restrict__ W, const float* __restrict__ bias,
  bf16* __restrict__ Y)
{
  __shared__ __align__(16) bf16 As[128*32];
  __shared__ __align__(16) bf16 Bs[128*32];
  const int tid = threadIdx.x, lane = tid & 63, w = tid >> 6;
  const int lr = lane & 15, lq = lane >> 4;
  const int mh = (w & 1) * 64, jh = (w >> 1) * 64;
  const int m0 = blockIdx.y * 128, j0 = blockIdx.x * 128;
  const int cA0 = w*128 + lane,      cA1 = w*128 + 64 + lane;
  const int r0 = cA0>>2, o0 = (cA0&3)*8, r1 = cA1>>2, o1 = (cA1&3)*8;
  bf16* lA0 = As + (w*2+0)*512; bf16* lA1 = As + (w*2+1)*512;
  bf16* lB0 = Bs + (w*2+0)*512; bf16* lB1 = Bs + (w*2+1)*512;
  floatx4 acc[4][4] = {};
  const bf16* Aseg[2] = { Zb + 256*1024, Hb + 256*1024 };
  #pragma unroll
  for (int seg=0; seg<2; seg++){
    const bf16* A = Aseg[seg];
    const bf16* Wb = W + seg*1024;
    for (int kb=0; kb<1024; kb+=32){
      stage16(A  + (size_t)(m0+r0)*1024 + kb + o0, lA0);
      stage16(A  + (size_t)(m0+r1)*1024 + kb + o1, lA1);
      stage16(Wb + (size_t)(j0+r0)*2048 + kb + o0, lB0);
      stage16(Wb + (size_t)(j0+r1)*2048 + kb + o1, lB1);
      __syncthreads();
      short8 af[4], bfr[4];
      #pragma unroll
      for (int f=0; f<4; f++){
        af[f]  = *(const short8*)&As[(mh + f*16 + lr)*32 + lq*8];
        bfr[f] = *(const short8*)&Bs[(jh + f*16 + lr)*32 + lq*8];
      }
      #pragma unroll
      for (int mf=0; mf<4; mf++)
        #pragma unroll
        for (int jf=0; jf<4; jf++)
          acc[mf][jf] = MFMA16(af[mf], bfr[jf], acc[mf][jf]);
      __syncthreads();
    }
  }
  #pragma unroll
  for (int mf=0; mf<4; mf++)
    #pragma unroll
    for (int jf=0; jf<4; jf++)
      #pragma unroll
      for (int i=0; i<4; i++){
        int m = m0 + mh + mf*16 + lq*4 + i;
        int j = j0 + jh + jf*16 + lr;
        Y[(size_t)m*1024 + j] = __float2bfloat16(ftanh(acc[mf][jf][i] + bias[j]));
      }
}

// obs_pred = Y1 @ dec_w2 + b -> out[b][t][0:512]: M=16384,N=512,K=1024. grid (4,128).
__global__ __launch_bounds__(256) void k_out1v2(
  const bf16* __restrict__ Yb, const bf16* __restrict__ W,
  const float* __restrict__ bias, float* __restrict__ out)
{
  __shared__ __align__(16) bf16 As[128*32];
  __shared__ __align__(16) bf16 Bs[128*32];
  const int tid = threadIdx.x, lane = tid & 63, w = tid >> 6;
  const int lr = lane & 15, lq = lane >> 4;
  const int mh = (w & 1) * 64, jh = (w >> 1) * 64;
  const int m0 = blockIdx.y * 128, j0 = blockIdx.x * 128;
  const int cA0 = w*128 + lane,      cA1 = w*128 + 64 + lane;
  const int r0 = cA0>>2, o0 = (cA0&3)*8, r1 = cA1>>2, o1 = (cA1&3)*8;
  bf16* lA0 = As + (w*2+0)*512; bf16* lA1 = As + (w*2+1)*512;
  bf16* lB0 = Bs + (w*2+0)*512; bf16* lB1 = Bs + (w*2+1)*512;
  floatx4 acc[4][4] = {};
  for (int kb=0; kb<1024; kb+=32){
    stage16(Yb + (size_t)(m0+r0)*1024 + kb + o0, lA0);
    stage16(Yb + (size_t)(m0+r1)*1024 + kb + o1, lA1);
    stage16(W  + (size_t)(j0+r0)*1024 + kb + o0, lB0);
    stage16(W  + (size_t)(j0+r1)*1024 + kb + o1, lB1);
    __syncthreads();
    short8 af[4], bfr[4];
    #pragma unroll
    for (int f=0; f<4; f++){
      af[f]  = *(const short8*)&As[(mh + f*16 + lr)*32 + lq*8];
      bfr[f] = *(const short8*)&Bs[(jh + f*16 + lr)*32 + lq*8];
    }
    #pragma unroll
    for (int mf=0; mf<4; mf++)
      #pragma unroll
      for (int jf=0; jf<4; jf++)
        acc[mf][jf] = MFMA16(af[mf], bfr[jf], acc[mf][jf]);
    __syncthreads();
  }
  #pragma unroll
  for (int mf=0; mf<4; mf++)
    #pragma unroll
    for (int jf=0; jf<4; jf++)
      #pragma unroll
      for (int i=0; i<4; i++){
        int m = m0 + mh + mf*16 + lq*4 + i;
        int j = j0 + jh + jf*16 + lr;
        int b = m & 255, t = m >> 8;
        out[(size_t)b*40960 + t*640 + j] = acc[mf][jf][i] + bias[j];
      }
}

// state decoder: din @ sd_w + b -> out[...,512:576]=mu, [...,576:640]=exp(ls)
__global__ __launch_bounds__(256) void k_sd(
  const bf16* __restrict__ Zb, const bf16* __restrict__ Hb,
  const bf16* __restrict__ W, const float* __restrict__ bias,
  float* __restrict__ out)
{
  int lane = threadIdx.x & 63, wave = threadIdx.x >> 6;
  int lr = lane & 15, lq = lane >> 4;
  int m0 = blockIdx.x * 32;
  int j0 = wave * 16;
  floatx4 aM[2] = {}, aL[2] = {};
  const bf16* Az = Zb + 256*1024;
  const bf16* Ah = Hb + 256*1024;
  #pragma unroll 2
  for (int kb=0; kb<1024; kb+=32){
    short8 a0 = ldf(Az + (m0+lr)*1024 + kb + lq*8);
    short8 a1 = ldf(Az + (m0+16+lr)*1024 + kb + lq*8);
    short8 bm = ldf(W + (size_t)(j0+lr)*2048 + kb + lq*8);
    short8 bl = ldf(W + (size_t)(j0+64+lr)*2048 + kb + lq*8);
    aM[0] = MFMA16(a0,bm,aM[0]); aM[1] = MFMA16(a1,bm,aM[1]);
    aL[0] = MFMA16(a0,bl,aL[0]); aL[1] = MFMA16(a1,bl,aL[1]);
  }
  #pragma unroll 2
  for (int kb=0; kb<1024; kb+=32){
    short8 a0 = ldf(Ah + (m0+lr)*1024 + kb + lq*8);
    short8 a1 = ldf(Ah + (m0+16+lr)*1024 + kb + lq*8);
    short8 bm = ldf(W + (size_t)(j0+lr)*2048 + 1024 + kb + lq*8);
    short8 bl = ldf(W + (size_t)(j0+64+lr)*2048 + 1024 + kb + lq*8);
    aM[0] = MFMA16(a0,bm,aM[0]); aM[1] = MFMA16(a1,bm,aM[1]);
    aL[0] = MFMA16(a0,bl,aL[0]); aL[1] = MFMA16(a1,bl,aL[1]);
  }
  #pragma unroll
  for (int rf=0;rf<2;rf++)
    #pragma unroll
    for (int i=0;i<4;i++){
      int m = m0 + rf*16 + lq*4 + i;
      int j = j0 + lr;
      int b = m & 255, t = m >> 8;
      out[b*40960 + t*640 + 512 + j] = aM[rf][i] + bias[j];
      out[b*40960 + t*640 + 576 + j] = __expf(aL[rf][i] + bias[64+j]);
    }
}

extern "C" void kernel_launch(void* const* d_in, const int* in_sizes, int n_in,
                              void* d_out, int out_size, void* d_ws, size_t ws_size,
                              hipStream_t stream)
{
  const float* obs    = (const float*)d_in[0];
  const float* state  = (const float*)d_in[1];
  const float* act    = (const float*)d_in[2];
  const float* eps0   = (const float*)d_in[3];
  const float* epss   = (const float*)d_in[4];
  const float* enc_w1 = (const float*)d_in[5];  const float* enc_b1 = (const float*)d_in[6];
  const float* enc_w2 = (const float*)d_in[7];  const float* enc_b2 = (const float*)d_in[8];
  const float* post_w1= (const float*)d_in[9];  const float* post_b1= (const float*)d_in[10];
  const float* post_w2= (const float*)d_in[11]; const float* post_b2= (const float*)d_in[12];
  const float* amlp_w1= (const float*)d_in[13]; const float* amlp_b1= (const float*)d_in[14];
  const float* amlp_w2= (const float*)d_in[15]; const float* amlp_b2= (const float*)d_in[16];
  const float* gwih   = (const float*)d_in[17];
  const float* gwhh   = (const float*)d_in[18];
  const float* gbih   = (const float*)d_in[19];
  const float* gbhh   = (const float*)d_in[20];
  const float* lsd_w1 = (const float*)d_in[21]; const float* lsd_b1 = (const float*)d_in[22];
  const float* lsd_w2 = (const float*)d_in[23]; const float* lsd_b2 = (const float*)d_in[24];
  const float* dec_w1 = (const float*)d_in[25]; const float* dec_b1 = (const float*)d_in[26];
  const float* dec_w2 = (const float*)d_in[27]; const float* dec_b2 = (const float*)d_in[28];
  const float* sd_w   = (const float*)d_in[29]; const float* sd_b   = (const float*)d_in[30];
  float* out = (float*)d_out;

  char* w = (char*)d_ws;
  size_t off = 0;
  auto alloc = [&](size_t elems)->bf16* {
    bf16* p = (bf16*)(w + off);
    off += ((elems*2 + 255)/256)*256;
    return p;
  };
  bf16* WzT      = alloc((size_t)3072*1024);
  bf16* WhT      = alloc((size_t)3072*1024);
  bf16* WaT      = alloc((size_t)3072*512);
  bf16* lsd_w1T  = alloc((size_t)1024*1024);
  bf16* lsd_w2T  = alloc((size_t)2048*1024);
  bf16* dec_w1T  = alloc((size_t)1024*2048);
  bf16* dec_w2T  = alloc((size_t)512*1024);
  bf16* sd_wT    = alloc((size_t)128*2048);
  bf16* enc_w1T  = alloc((size_t)512*512);
  bf16* enc_w2T  = alloc((size_t)256*512);
  bf16* post_w1sT= alloc((size_t)1024*192);
  bf16* post_w2T = alloc((size_t)2048*1024);
  bf16* amlp_w2T = alloc((size_t)512*512);
  bf16* obsb     = alloc((size_t)256*512);
  bf16* E1       = alloc((size_t)256*512);
  bf16* PIN      = alloc((size_t)256*192);
  bf16* P1       = alloc((size_t)256*1024);
  bf16* X        = alloc((size_t)256*1024);
  bf16* Zbuf     = alloc((size_t)65*256*1024);
  bf16* Hbuf     = alloc((size_t)65*256*1024);
  bf16* AEb      = alloc((size_t)16384*512);
  bf16* Y1       = alloc((size_t)16384*1024);
  bf16* H1       = Y1;   // H1 (16 MiB) dead before Y1 is written

  // --- weight prep ---
  #define TP(src, dst, R, C) k_transpose<<<dim3((C)/32,(R)/32),256,0,stream>>>((src),(dst),(R),(C))
  TP(enc_w1, enc_w1T, 512, 512);
  TP(enc_w2, enc_w2T, 512, 256);
  TP(post_w1 + (size_t)1024*1024, post_w1sT, 192, 1024);
  TP(post_w2, post_w2T, 1024, 2048);
  TP(amlp_w2, amlp_w2T, 512, 512);
  TP(gwih, WzT, 1024, 3072);
  TP(gwih + (size_t)1024*3072, WaT, 512, 3072);
  TP(gwhh, WhT, 1024, 3072);
  TP(lsd_w1, lsd_w1T, 1024, 1024);
  TP(lsd_w2, lsd_w2T, 1024, 2048);
  TP(dec_w1, dec_w1T, 2048, 1024);
  TP(dec_w2, dec_w2T, 1024, 512);
  TP(sd_w, sd_wT, 2048, 128);
  #undef TP

  k_cast<<<512,256,0,stream>>>(obs, obsb, 256*512);
  k_cast_state<<<64,256,0,stream>>>(state, PIN);
  k_acth1<<<32768,256,0,stream>>>(act, amlp_w1, amlp_b1, H1);

  hipMemsetAsync(Hbuf, 0, (size_t)256*1024*2, stream);

  k_gemm16<<<dim3(8,16),256,0,stream>>>(obsb, 512, enc_w1T, enc_b1, E1, 512, 0, 512, 1);
  k_gemm16<<<dim3(2,16),256,0,stream>>>(E1, 512, enc_w2T, enc_b2, PIN, 192, 64, 512, 0);
  k_gemm16<<<dim3(16,16),256,0,stream>>>(PIN, 192, post_w1sT, post_b1, P1, 1024, 0, 192, 1);
  k_gauss<<<dim3(16,16),256,0,stream>>>(P1, post_w2T, post_b2, eps0, Zbuf, 1024);
  k_aev2<<<dim3(4,128),256,0,stream>>>(H1, amlp_w2T, amlp_b2, AEb);

  // --- persistent cooperative scan: 1 launch instead of 192 ---
  {
    void* sa[] = { (void*)&Zbuf, (void*)&Hbuf, (void*)&AEb,
                   (void*)&WzT, (void*)&WhT, (void*)&WaT,
                   (void*)&gbih, (void*)&gbhh,
                   (void*)&lsd_w1T, (void*)&lsd_b1,
                   (void*)&lsd_w2T, (void*)&lsd_b2,
                   (void*)&epss, (void*)&X };
    hipLaunchCooperativeKernel((void*)k_scan, dim3(256), dim3(256), sa, 0, stream);
  }

  // --- decode ---
  k_dec1v2<<<dim3(8,128),256,0,stream>>>(Zbuf, Hbuf, dec_w1T, dec_b1, Y1);
  k_out1v2<<<dim3(4,128),256,0,stream>>>(Y1, dec_w2T, dec_b2, out);
  k_sd<<<512,256,0,stream>>>(Zbuf, Hbuf, sd_wT, sd_b, out);
}